// Round 5
// baseline (309.181 us; speedup 1.0000x reference)
//
#include <hip/hip_runtime.h>

// Chamfer distance K=1 NN, both directions. N=4, P1=P2=8192, D=3, fp32.
//
// Numerics: bitwise-replicate numpy fp32:
//   d2 = (sp + sq) - 2.0f * (((px*qx) + (py*qy)) + (pz*qz))
// fp contract OFF for all C-level FP; distance math in v_pk_*_f32 inline asm
// (per-element rounding identical to scalar VALU). mul+sub folded to
// fma(-2,dot,t1): bitwise-safe (x2.0 exact). min/min3 exactly associative.
//
// Structure:
//   prep : SoA [X|Y|Z|S] (65536 each) in ws; S = ((x*x)+(y*y))+(z*z).
//   nn   : 1024 blocks x 512 thr = 64 queries x 8 waves; wave w scans
//          targets [w*1024,(w+1)*1024). Per 64-target supergroup: ONE
//          address per array, float4 loads at immediate offsets (no
//          per-load addr VALU). Packed math all-VGPR. Running v_min3
//          per 32-target group + winning-group tracking; exact index via
//          descending scalar rescan (bitwise-identical so == is exact);
//          LDS reduce across 8 waves (smallest-index tie-break); direct out.

typedef float v2f __attribute__((ext_vector_type(2)));

#define NPTS 32768
#define TSEG 1024

#define OFF_X 0
#define OFF_Y 65536
#define OFF_Z 131072
#define OFF_S 196608

__device__ __forceinline__ v2f pk_mul(v2f a, v2f b) {
    v2f d; asm("v_pk_mul_f32 %0, %1, %2" : "=v"(d) : "v"(a), "v"(b)); return d;
}
__device__ __forceinline__ v2f pk_add(v2f a, v2f b) {
    v2f d; asm("v_pk_add_f32 %0, %1, %2" : "=v"(d) : "v"(a), "v"(b)); return d;
}
__device__ __forceinline__ v2f pk_fma(v2f a, v2f b, v2f c) {
    v2f d; asm("v_pk_fma_f32 %0, %1, %2, %3" : "=v"(d) : "v"(a), "v"(b), "v"(c)); return d;
}
__device__ __forceinline__ float vmin3(float a, float b, float c) {
    float d; asm("v_min3_f32 %0, %1, %2, %3" : "=v"(d) : "v"(a), "v"(b), "v"(c)); return d;
}

__global__ __launch_bounds__(256) void chamfer_prep(const float* __restrict__ x,
                                                    const float* __restrict__ y,
                                                    float* __restrict__ ws) {
#pragma clang fp contract(off)
    int i = blockIdx.x * 256 + threadIdx.x;     // 0..65535
    const float* src = (i < NPTS) ? x : y;
    int j = (i < NPTS) ? i : (i - NPTS);
    float a = src[j * 3 + 0];
    float b = src[j * 3 + 1];
    float c = src[j * 3 + 2];
    ws[OFF_X + i] = a;
    ws[OFF_Y + i] = b;
    ws[OFF_Z + i] = c;
    ws[OFF_S + i] = ((a * a) + (b * b)) + (c * c);
}

__global__ __launch_bounds__(512, 8) void chamfer_nn(const float* __restrict__ ws,
                                                     float* __restrict__ out) {
#pragma clang fp contract(off)
    int b   = blockIdx.x;            // 0..1023
    int dir = b >> 9;                // 0: x->y, 1: y->x
    int r   = b & 511;
    int n   = r >> 7;                // batch
    int qg  = r & 127;               // query group of 64
    int lane = threadIdx.x & 63;
    int wv   = threadIdx.x >> 6;     // wave id 0..7 = target segment

    const float* X = ws + OFF_X;
    const float* Y = ws + OFF_Y;
    const float* Z = ws + OFF_Z;
    const float* S = ws + OFF_S;

    int qidx   = (dir ? NPTS : 0) + n * 8192 + qg * 64 + lane;
    int tcbase = (dir ? 0 : NPTS) + n * 8192;   // target cloud base
    int tbase  = tcbase + wv * TSEG;            // this wave's 1024-target segment

    float px = X[qidx], py = Y[qidx], pz = Z[qidx], sp = S[qidx];
    v2f px2 = {px, px}, py2 = {py, py}, pz2 = {pz, pz}, sp2 = {sp, sp};
    v2f n2  = {-2.0f, -2.0f};

    float best = __builtin_inff();
    int bgrp = 0;

    for (int sg = 0; sg < TSEG / 64; ++sg) {    // 16 supergroups of 64 targets
        int t0 = tbase + sg * 64;
        const float4* Xq = (const float4*)(X + t0);
        const float4* Yq = (const float4*)(Y + t0);
        const float4* Zq = (const float4*)(Z + t0);
        const float4* Sq = (const float4*)(S + t0);
#pragma unroll
        for (int h = 0; h < 2; ++h) {           // 2 groups of 32 targets
            float m = __builtin_inff();
#pragma unroll
            for (int i = 0; i < 8; ++i) {       // 8 float4 = 32 targets
                int k = h * 8 + i;              // imm offset k*16 bytes
                float4 xv = Xq[k];
                float4 yv = Yq[k];
                float4 zv = Zq[k];
                float4 sv = Sq[k];
                v2f xa = {xv.x, xv.y}, xb = {xv.z, xv.w};
                v2f ya = {yv.x, yv.y}, yb = {yv.z, yv.w};
                v2f za = {zv.x, zv.y}, zb = {zv.z, zv.w};
                v2f sa = {sv.x, sv.y}, sb = {sv.z, sv.w};
                v2f da = pk_add(pk_add(pk_mul(xa, px2), pk_mul(ya, py2)), pk_mul(za, pz2));
                v2f ta = pk_fma(n2, da, pk_add(sa, sp2));
                v2f db = pk_add(pk_add(pk_mul(xb, px2), pk_mul(yb, py2)), pk_mul(zb, pz2));
                v2f tb = pk_fma(n2, db, pk_add(sb, sp2));
                float pa = fminf(ta.x, ta.y);
                float pb = fminf(tb.x, tb.y);
                m = vmin3(pa, pb, m);
            }
            if (m < best) { best = m; bgrp = sg * 2 + h; }  // strict <: earliest group
        }
    }

    // rescan winning 32-target group; scalar VALU rounds identically to
    // packed, so == against best is exact. Descending j: final = smallest idx.
    int t0 = tbase + bgrp * 32;
    int idx = t0;
    for (int j = 31; j >= 0; --j) {
        float qx = X[t0 + j], qy = Y[t0 + j], qz = Z[t0 + j], qs = S[t0 + j];
        float dot = ((px * qx) + (py * qy)) + (pz * qz);
        float t1  = sp + qs;
        float t   = fmaf(-2.0f, dot, t1);
        if (t == best) idx = t0 + j;
    }

    // cross-wave reduction (8 waves = 8 ascending target segments)
    __shared__ float sval[512];
    __shared__ int   sidx[512];
    sval[threadIdx.x] = best;
    sidx[threadIdx.x] = idx;
    __syncthreads();

    if (threadIdx.x < 64) {
        float bv = sval[threadIdx.x];
        int   bi = sidx[threadIdx.x];
#pragma unroll
        for (int w = 1; w < 8; ++w) {
            float v  = sval[w * 64 + threadIdx.x];
            int   i2 = sidx[w * 64 + threadIdx.x];
            if (v < bv || (v == bv && i2 < bi)) { bv = v; bi = i2; }
        }
        // out layout: cham_x[32768] cham_y[32768] idx_x[32768] idx_y[32768]
        int distoff = dir ? 32768 : 0;
        int idxoff  = dir ? 98304 : 65536;
        int o = n * 8192 + qg * 64 + threadIdx.x;
        out[distoff + o] = bv;
        out[idxoff + o]  = (float)(bi - tcbase);
    }
}

extern "C" void kernel_launch(void* const* d_in, const int* in_sizes, int n_in,
                              void* d_out, int out_size, void* d_ws, size_t ws_size,
                              hipStream_t stream) {
    const float* x = (const float*)d_in[0];
    const float* y = (const float*)d_in[1];
    float* ws  = (float*)d_ws;
    float* out = (float*)d_out;

    chamfer_prep<<<256, 256, 0, stream>>>(x, y, ws);
    chamfer_nn<<<1024, 512, 0, stream>>>(ws, out);
}

// Round 6
// 152.936 us; speedup vs baseline: 2.0216x; 2.0216x over previous
//
#include <hip/hip_runtime.h>

// Chamfer distance K=1 NN, both directions. N=4, P1=P2=8192, D=3, fp32.
//
// Numerics: bitwise-replicate numpy fp32:
//   d2 = (sp + sq) - 2.0f * (((px*qx) + (py*qy)) + (pz*qz))
// fp contract OFF for all C-level FP; distance math in v_pk_*_f32 inline asm
// (per-element rounding identical to scalar VALU); mul+sub folded to
// fma(-2,dot,t1) (bitwise-safe: x2.0 exact). min/min3 exactly associative.
//
// Structure:
//   prep : SoA [X|Y|Z|S] (65536 floats each) in ws; S = ((x*x)+(y*y))+(z*z).
//   nn   : 1024 blocks x 512 thr = 64 queries (per-lane) x 8 waves; wave w
//          scans targets [w*1024,(w+1)*1024). Targets fetched with EXPLICIT
//          s_load_dwordx16 inline asm (wave-uniform base in SGPR pair,
//          imm offsets 0/256K/512K/768K select the X/Y/Z/S arrays) -> data
//          lands in SGPR tuples, consumed directly by v_pk_* ("s" source,
//          zero readfirstlane). s_waitcnt lgkmcnt(0) tied via "+s" operands;
//          next group's loads issue right after this group's math (dummy
//          "v" dep pins the order) for in-wave overlap.
//          Per-16-target min tree (v_min3) + winning-group tracking; exact
//          index via descending scalar rescan (bitwise-identical so == is
//          exact); LDS reduce across 8 waves (smallest-index tie-break).

typedef float v2f  __attribute__((ext_vector_type(2)));
typedef float v16f __attribute__((ext_vector_type(16)));

#define NPTS 32768
#define TSEG 1024

#define OFF_X 0
#define OFF_Y 65536
#define OFF_Z 131072
#define OFF_S 196608

__device__ __forceinline__ v2f pk_mul_sv(v2f s, v2f v) {
    v2f d; asm("v_pk_mul_f32 %0, %1, %2" : "=v"(d) : "s"(s), "v"(v)); return d;
}
__device__ __forceinline__ v2f pk_add_sv(v2f s, v2f v) {
    v2f d; asm("v_pk_add_f32 %0, %1, %2" : "=v"(d) : "s"(s), "v"(v)); return d;
}
__device__ __forceinline__ v2f pk_add_vv(v2f a, v2f b) {
    v2f d; asm("v_pk_add_f32 %0, %1, %2" : "=v"(d) : "v"(a), "v"(b)); return d;
}
__device__ __forceinline__ v2f pk_fma_vvv(v2f a, v2f b, v2f c) {
    v2f d; asm("v_pk_fma_f32 %0, %1, %2, %3" : "=v"(d) : "v"(a), "v"(b), "v"(c)); return d;
}
__device__ __forceinline__ float vmin3(float a, float b, float c) {
    float d; asm("v_min3_f32 %0, %1, %2, %3" : "=v"(d) : "v"(a), "v"(b), "v"(c)); return d;
}

__global__ __launch_bounds__(256) void chamfer_prep(const float* __restrict__ x,
                                                    const float* __restrict__ y,
                                                    float* __restrict__ ws) {
#pragma clang fp contract(off)
    int i = blockIdx.x * 256 + threadIdx.x;     // 0..65535
    const float* src = (i < NPTS) ? x : y;
    int j = (i < NPTS) ? i : (i - NPTS);
    float a = src[j * 3 + 0];
    float b = src[j * 3 + 1];
    float c = src[j * 3 + 2];
    ws[OFF_X + i] = a;
    ws[OFF_Y + i] = b;
    ws[OFF_Z + i] = c;
    ws[OFF_S + i] = ((a * a) + (b * b)) + (c * c);
}

// Issue the 4 scalar loads for one 16-target group. Base Xq is the X-array
// address of the group; Y/Z/S arrays are at +256KB/+512KB/+768KB (SoA).
// dep: dummy VGPR input that pins this asm AFTER the math that produced it.
#define SLOAD(dep_)                                                      \
    asm volatile("s_load_dwordx16 %0, %4, 0\n\t"                         \
                 "s_load_dwordx16 %1, %4, 262144\n\t"                    \
                 "s_load_dwordx16 %2, %4, 524288\n\t"                    \
                 "s_load_dwordx16 %3, %4, 786432"                        \
                 : "=s"(xs), "=s"(ys), "=s"(zs), "=s"(ss)                \
                 : "s"(Xq), "v"(dep_))

#define SWAIT()                                                          \
    asm volatile("s_waitcnt lgkmcnt(0)"                                  \
                 : "+s"(xs), "+s"(ys), "+s"(zs), "+s"(ss))

__global__ __launch_bounds__(512, 8) void chamfer_nn(const float* __restrict__ ws,
                                                     float* __restrict__ out) {
#pragma clang fp contract(off)
    int b   = blockIdx.x;            // 0..1023
    int dir = b >> 9;                // 0: x->y, 1: y->x
    int r   = b & 511;
    int n   = r >> 7;                // batch
    int qg  = r & 127;               // query group of 64
    int lane = threadIdx.x & 63;
    int wv   = threadIdx.x >> 6;     // wave id 0..7 = target segment

    const float* X = ws + OFF_X;
    const float* Y = ws + OFF_Y;
    const float* Z = ws + OFF_Z;
    const float* S = ws + OFF_S;

    int qidx   = (dir ? NPTS : 0) + n * 8192 + qg * 64 + lane;
    int tcbase = (dir ? 0 : NPTS) + n * 8192;   // target cloud base
    int tb     = __builtin_amdgcn_readfirstlane(tcbase + wv * TSEG);

    float px = X[qidx], py = Y[qidx], pz = Z[qidx], sp = S[qidx];
    v2f px2 = {px, px}, py2 = {py, py}, pz2 = {pz, pz}, sp2 = {sp, sp};
    v2f n2v = {-2.0f, -2.0f};

    const float* Xq = X + tb;        // uniform -> SGPR pair
    v16f xs, ys, zs, ss;

    float best = __builtin_inff();
    int bgrp = 0;

    SLOAD(0.0f);                     // prologue: group 0
    Xq += 16;

#pragma unroll 1
    for (int g = 0; g < TSEG / 16; ++g) {
        SWAIT();
        float pm[8];
#pragma unroll
        for (int i = 0; i < 8; ++i) {
            v2f xa = {xs[2 * i], xs[2 * i + 1]};
            v2f ya = {ys[2 * i], ys[2 * i + 1]};
            v2f za = {zs[2 * i], zs[2 * i + 1]};
            v2f sa = {ss[2 * i], ss[2 * i + 1]};
            v2f d1  = pk_mul_sv(xa, px2);
            v2f d2  = pk_mul_sv(ya, py2);
            v2f d3  = pk_mul_sv(za, pz2);
            v2f a1  = pk_add_vv(d1, d2);
            v2f dot = pk_add_vv(a1, d3);
            v2f t1  = pk_add_sv(sa, sp2);
            v2f t   = pk_fma_vvv(n2v, dot, t1);
            pm[i] = fminf(t[0], t[1]);
        }
        float m = vmin3(pm[0], pm[1], pm[2]);
        m = vmin3(pm[3], pm[4], m);
        m = vmin3(pm[5], pm[6], m);
        m = fminf(pm[7], m);
        if (g < TSEG / 16 - 1) {     // issue next group's loads (after math: dep m)
            SLOAD(m);
            Xq += 16;
        }
        if (m < best) { best = m; bgrp = g; }   // strict <: earliest group wins
    }

    // rescan winning 16-target group; scalar VALU rounds identically to
    // packed, so == against best is exact. Descending j: final = smallest idx.
    int t0 = tb + bgrp * 16;
    int idx = t0;
    for (int j = 15; j >= 0; --j) {
        float qx = X[t0 + j], qy = Y[t0 + j], qz = Z[t0 + j], qs = S[t0 + j];
        float dot = ((px * qx) + (py * qy)) + (pz * qz);
        float t1  = sp + qs;
        float t   = fmaf(-2.0f, dot, t1);
        if (t == best) idx = t0 + j;
    }

    // cross-wave reduction (8 waves = 8 ascending target segments)
    __shared__ float sval[512];
    __shared__ int   sidx[512];
    sval[threadIdx.x] = best;
    sidx[threadIdx.x] = idx;
    __syncthreads();

    if (threadIdx.x < 64) {
        float bv = sval[threadIdx.x];
        int   bi = sidx[threadIdx.x];
#pragma unroll
        for (int w = 1; w < 8; ++w) {
            float v  = sval[w * 64 + threadIdx.x];
            int   i2 = sidx[w * 64 + threadIdx.x];
            if (v < bv || (v == bv && i2 < bi)) { bv = v; bi = i2; }
        }
        // out layout: cham_x[32768] cham_y[32768] idx_x[32768] idx_y[32768]
        int distoff = dir ? 32768 : 0;
        int idxoff  = dir ? 98304 : 65536;
        int o = n * 8192 + qg * 64 + threadIdx.x;
        out[distoff + o] = bv;
        out[idxoff + o]  = (float)(bi - tcbase);
    }
}

extern "C" void kernel_launch(void* const* d_in, const int* in_sizes, int n_in,
                              void* d_out, int out_size, void* d_ws, size_t ws_size,
                              hipStream_t stream) {
    const float* x = (const float*)d_in[0];
    const float* y = (const float*)d_in[1];
    float* ws  = (float*)d_ws;
    float* out = (float*)d_out;

    chamfer_prep<<<256, 256, 0, stream>>>(x, y, ws);
    chamfer_nn<<<1024, 512, 0, stream>>>(ws, out);
}